// Round 1
// 81.657 us; speedup vs baseline: 1.0097x; 1.0097x over previous
//
#include <hip/hip_runtime.h>

#define Bv 16
#define Cv 64
#define Sv 2048
#define NSEG 64           // pli segments
#define SSEG 32           // samples per pli segment
#define ROWS 68           // pli LDS row stride in words (64 ch + 4 pad)
#define NTILE 144         // triangle tiles: dq in 0..8 x qi in 0..15

// Forward DIF butterfly: u' = u+v ; v' = (u-v)*w
__device__ __forceinline__ void bf_f(float2& u, float2& v, const float2 w) {
    const float dr = u.x - v.x, di = u.y - v.y;
    u.x += v.x; u.y += v.y;
    v.x = dr * w.x - di * w.y;
    v.y = dr * w.y + di * w.x;
}
// Inverse DIT butterfly: v' = v*conj(w) ; u' = u+v' ; l' = u-v'
__device__ __forceinline__ void bf_i(float2& u, float2& v, const float2 w) {
    const float vr = v.x * w.x + v.y * w.y;
    const float vi = v.y * w.x - v.x * w.y;
    v.x = u.x - vr; v.y = u.y - vi;
    u.x += vr; u.y += vi;
}
__device__ __forceinline__ float2 csq(const float2 a) {
    return make_float2(a.x * a.x - a.y * a.y, 2.0f * a.x * a.y);
}
__device__ __forceinline__ float2 cm1(const float2 a) {   // a * e^{-i pi/4}
    const float cq = 0.70710678118654752f;
    return make_float2(cq * (a.x + a.y), cq * (a.y - a.x));
}
__device__ __forceinline__ float2 cmi(const float2 a) {   // a * e^{-i pi/2}
    return make_float2(a.y, -a.x);
}
// Bank-conflict-breaking storage map for the FFT scratch: n -> n + n/8.
__device__ __forceinline__ int pad(int n) { return n + (n >> 3); }

// ---------------------------------------------------------------------------
// Kernel 1: paired-channel Hilbert transform (verified R7 FFT logic) with a
// NEW epilogue: instead of storing H(x), quantize the instantaneous phase to
// 32-bit fixed point, u = atan2f(H(x), x) * 2^31/pi  (mod 2^32 == mod 2*pi).
// Downstream, sign(sin(theta_i - theta_j)) < 0  <=>  (int32)(u_i - u_j) < 0.
// This halves the data volume kernel 2 must move (one word per (ch,s)).
// ---------------------------------------------------------------------------
__global__ __launch_bounds__(256) void hilbert_kernel(const float* __restrict__ x,
                                                      unsigned int* __restrict__ u) {
    __shared__ float2 zz[Sv + Sv / 8];   // 2304 float2 = 18 KB (padded map)
    const int t = threadIdx.x;
    const int c0 = blockIdx.x * 2;
    const float* x0 = x + (size_t)c0 * Sv;
    const float* x1 = x0 + Sv;

    const float PI = 3.14159265358979323846f;
    float2 bA4, bB4, bC2;
    sincosf(-PI * (float)t * (1.0f / 1024.0f), &bA4.y, &bA4.x);
    sincosf(-PI * (float)(t & 31) * (1.0f / 128.0f), &bB4.y, &bB4.x);
    sincosf(-PI * (float)(t & 7) * (1.0f / 16.0f), &bC2.y, &bC2.x);
    const float2 bA2 = csq(bA4), bA1 = csq(bA2);
    const float2 bB2 = csq(bB4), bB1 = csq(bB2);
    const float2 bC1 = csq(bC2);

    float2 z[8];
    #pragma unroll
    for (int k = 0; k < 8; ++k)
        z[k] = make_float2(x0[t + 256 * k], x1[t + 256 * k]);

    // ---- fwd halves 1024,512,256 (stride 256) ----
    {
        const float2 w1 = cm1(bA4);
        bf_f(z[0], z[4], bA4);      bf_f(z[1], z[5], w1);
        bf_f(z[2], z[6], cmi(bA4)); bf_f(z[3], z[7], cmi(w1));
        const float2 wB = cmi(bA2);
        bf_f(z[0], z[2], bA2); bf_f(z[1], z[3], wB);
        bf_f(z[4], z[6], bA2); bf_f(z[5], z[7], wB);
        bf_f(z[0], z[1], bA1); bf_f(z[2], z[3], bA1);
        bf_f(z[4], z[5], bA1); bf_f(z[6], z[7], bA1);
    }
    #pragma unroll
    for (int k = 0; k < 8; ++k) zz[pad(t + 256 * k)] = z[k];
    __syncthreads();

    // ---- fwd halves 128,64,32 (stride 32) ----
    {
        const int r = t & 31, base = (t >> 5) * 256 + r;
        #pragma unroll
        for (int k = 0; k < 8; ++k) z[k] = zz[pad(base + 32 * k)];
        const float2 w1 = cm1(bB4);
        bf_f(z[0], z[4], bB4);      bf_f(z[1], z[5], w1);
        bf_f(z[2], z[6], cmi(bB4)); bf_f(z[3], z[7], cmi(w1));
        const float2 wB = cmi(bB2);
        bf_f(z[0], z[2], bB2); bf_f(z[1], z[3], wB);
        bf_f(z[4], z[6], bB2); bf_f(z[5], z[7], wB);
        bf_f(z[0], z[1], bB1); bf_f(z[2], z[3], bB1);
        bf_f(z[4], z[5], bB1); bf_f(z[6], z[7], bB1);
        #pragma unroll
        for (int k = 0; k < 8; ++k) zz[pad(base + 32 * k)] = z[k];
    }
    __syncthreads();

    // ---- fwd halves 16,8 (stride 8; two 4-sets) ----
    {
        const int r = t & 7, base0 = (t >> 3) * 32 + r, base1 = base0 + 1024;
        #pragma unroll
        for (int k = 0; k < 4; ++k) {
            z[k] = zz[pad(base0 + 8 * k)];
            z[4 + k] = zz[pad(base1 + 8 * k)];
        }
        const float2 wB = cmi(bC2);
        bf_f(z[0], z[2], bC2); bf_f(z[1], z[3], wB);
        bf_f(z[4], z[6], bC2); bf_f(z[5], z[7], wB);
        bf_f(z[0], z[1], bC1); bf_f(z[2], z[3], bC1);
        bf_f(z[4], z[5], bC1); bf_f(z[6], z[7], bC1);
        #pragma unroll
        for (int k = 0; k < 4; ++k) {
            zz[pad(base0 + 8 * k)] = z[k];
            zz[pad(base1 + 8 * k)] = z[4 + k];
        }
    }
    __syncthreads();

    // ---- fused: fwd 4,2,1 ; Hilbert filter * 1/N ; inv 1,2,4 ----
    {
        const int base = 8 * t;
        #pragma unroll
        for (int k = 0; k < 8; ++k) z[k] = zz[pad(base + k)];
        const float cq = 0.70710678118654752f;
        const float2 W1  = make_float2(1.0f, 0.0f);
        const float2 W41 = make_float2(cq, -cq);
        const float2 W42 = make_float2(0.0f, -1.0f);
        const float2 W43 = make_float2(-cq, -cq);
        bf_f(z[0], z[4], W1);  bf_f(z[1], z[5], W41);
        bf_f(z[2], z[6], W42); bf_f(z[3], z[7], W43);
        bf_f(z[0], z[2], W1); bf_f(z[1], z[3], W42);
        bf_f(z[4], z[6], W1); bf_f(z[5], z[7], W42);
        bf_f(z[0], z[1], W1); bf_f(z[2], z[3], W1);
        bf_f(z[4], z[5], W1); bf_f(z[6], z[7], W1);
        const float inv = 1.0f / (float)Sv;
        #pragma unroll
        for (int k = 0; k < 8; ++k) {
            const int kk = (int)(__brev((unsigned)(base + k)) >> 21);   // logical index!
            const float m = (kk == 0 || kk == Sv / 2) ? inv : (kk < Sv / 2 ? 2.0f * inv : 0.0f);
            z[k].x *= m; z[k].y *= m;
        }
        bf_i(z[0], z[1], W1); bf_i(z[2], z[3], W1);
        bf_i(z[4], z[5], W1); bf_i(z[6], z[7], W1);
        bf_i(z[0], z[2], W1); bf_i(z[1], z[3], W42);
        bf_i(z[4], z[6], W1); bf_i(z[5], z[7], W42);
        bf_i(z[0], z[4], W1);  bf_i(z[1], z[5], W41);
        bf_i(z[2], z[6], W42); bf_i(z[3], z[7], W43);
        #pragma unroll
        for (int k = 0; k < 8; ++k) zz[pad(base + k)] = z[k];
    }
    __syncthreads();

    // ---- inv halves 8,16 (stride 8; two 4-sets) ----
    {
        const int r = t & 7, base0 = (t >> 3) * 32 + r, base1 = base0 + 1024;
        #pragma unroll
        for (int k = 0; k < 4; ++k) {
            z[k] = zz[pad(base0 + 8 * k)];
            z[4 + k] = zz[pad(base1 + 8 * k)];
        }
        bf_i(z[0], z[1], bC1); bf_i(z[2], z[3], bC1);
        bf_i(z[4], z[5], bC1); bf_i(z[6], z[7], bC1);
        const float2 wB = cmi(bC2);
        bf_i(z[0], z[2], bC2); bf_i(z[1], z[3], wB);
        bf_i(z[4], z[6], bC2); bf_i(z[5], z[7], wB);
        #pragma unroll
        for (int k = 0; k < 4; ++k) {
            zz[pad(base0 + 8 * k)] = z[k];
            zz[pad(base1 + 8 * k)] = z[4 + k];
        }
    }
    __syncthreads();

    // ---- inv halves 32,64,128 (stride 32) ----
    {
        const int r = t & 31, base = (t >> 5) * 256 + r;
        #pragma unroll
        for (int k = 0; k < 8; ++k) z[k] = zz[pad(base + 32 * k)];
        bf_i(z[0], z[1], bB1); bf_i(z[2], z[3], bB1);
        bf_i(z[4], z[5], bB1); bf_i(z[6], z[7], bB1);
        const float2 wB = cmi(bB2);
        bf_i(z[0], z[2], bB2); bf_i(z[1], z[3], wB);
        bf_i(z[4], z[6], bB2); bf_i(z[5], z[7], wB);
        const float2 w1 = cm1(bB4);
        bf_i(z[0], z[4], bB4);      bf_i(z[1], z[5], w1);
        bf_i(z[2], z[6], cmi(bB4)); bf_i(z[3], z[7], cmi(w1));
        #pragma unroll
        for (int k = 0; k < 8; ++k) zz[pad(base + 32 * k)] = z[k];
    }
    __syncthreads();

    // ---- inv halves 256,512,1024 (stride 256) + fused phase-quantize write ----
    {
        #pragma unroll
        for (int k = 0; k < 8; ++k) z[k] = zz[pad(t + 256 * k)];
        bf_i(z[0], z[1], bA1); bf_i(z[2], z[3], bA1);
        bf_i(z[4], z[5], bA1); bf_i(z[6], z[7], bA1);
        const float2 wB = cmi(bA2);
        bf_i(z[0], z[2], bA2); bf_i(z[1], z[3], wB);
        bf_i(z[4], z[6], bA2); bf_i(z[5], z[7], wB);
        const float2 w1 = cm1(bA4);
        bf_i(z[0], z[4], bA4);      bf_i(z[1], z[5], w1);
        bf_i(z[2], z[6], cmi(bA4)); bf_i(z[3], z[7], cmi(w1));
        unsigned int* u0 = u + (size_t)c0 * Sv;
        unsigned int* u1 = u0 + Sv;
        const float SC = 683565275.576f;   // 2^31 / pi ; uniform scale, sign-preserving
        #pragma unroll
        for (int k = 0; k < 8; ++k) {
            const int n = t + 256 * k;
            const float xa = x0[n], xb = x1[n];
            const float ha = z[k].y - xb;   // H(x_a) = Im(w) - x_b
            const float hb = xa - z[k].x;   // H(x_b) = x_a - Re(w)
            u0[n] = (unsigned int)__float2int_rz(atan2f(ha, xa) * SC);
            u1[n] = (unsigned int)__float2int_rz(atan2f(hb, xb) * SC);
        }
    }
}

// ---------------------------------------------------------------------------
// Kernel 2: PLI negative-sign partial counts over fixed-point phases.
// Same triangle tiling as before; data per (ch,s) is now ONE word instead of
// two floats: LDS reads per thread 128 -> 64, inner op 4 -> 3 VALU/pair.
// sign(sin(th_i - th_j)) < 0  <=>  ((u_i - u_j) mod 2^32) >= 2^31.
// ---------------------------------------------------------------------------
__global__ __launch_bounds__(256) void pli_count_kernel(const unsigned int* __restrict__ u,
                                                        unsigned int* __restrict__ part) {
    __shared__ __align__(16) unsigned int uL[SSEG * ROWS];   // 8.7 KB
    const int blk = blockIdx.x;                 // b*NSEG + seg
    const int seg = blk & (NSEG - 1);
    const int b = blk >> 6;
    const int t = threadIdx.x;
    const unsigned int* ub = u + (size_t)b * Cv * Sv + seg * SSEG;

    for (int e = t; e < Cv * SSEG; e += 256) {
        const int ch = e >> 5;
        const int s = e & (SSEG - 1);
        uL[s * ROWS + ch] = ub[(size_t)ch * Sv + s];
    }
    __syncthreads();

    if (t < NTILE) {
        const int qi = t & 15;
        const int dq = t >> 4;                  // 0..8
        const int i0 = qi * 4;
        const int j0 = ((qi + dq) & 15) * 4;
        int neg[4][4] = {};

        #pragma unroll 4
        for (int s = 0; s < SSEG; ++s) {
            const uint4 ui = *(const uint4*)&uL[s * ROWS + i0];
            const uint4 uj = *(const uint4*)&uL[s * ROWS + j0];
            const unsigned int uia[4] = {ui.x, ui.y, ui.z, ui.w};
            const unsigned int uja[4] = {uj.x, uj.y, uj.z, uj.w};
            #pragma unroll
            for (int a = 0; a < 4; ++a) {
                #pragma unroll
                for (int c = 0; c < 4; ++c) {
                    // wrapped phase diff negative <=> top bit of (uia-uja)
                    neg[a][c] += (int)((uia[a] - uja[c]) >> 31);
                }
            }
        }

        unsigned int* Pb = part + ((size_t)blk * NTILE + t) * 4;
        unsigned int pk[4];
        #pragma unroll
        for (int a = 0; a < 4; ++a)
            pk[a] = (unsigned)neg[a][0] | ((unsigned)neg[a][1] << 8)
                  | ((unsigned)neg[a][2] << 16) | ((unsigned)neg[a][3] << 24);
        *(uint4*)Pb = make_uint4(pk[0], pk[1], pk[2], pk[3]);
    }
}

// ---------------------------------------------------------------------------
// Kernel 3: reduce triangle partials -> PLI (unchanged).
// ---------------------------------------------------------------------------
__global__ __launch_bounds__(256) void finalize_kernel(const unsigned char* __restrict__ part,
                                                       float* __restrict__ out) {
    const int idx = blockIdx.x * 256 + threadIdx.x;   // 65536 = B*C*C
    const int b = idx >> 12;
    const int ij = idx & 4095;
    const int i = ij >> 6, j = ij & 63;
    const int qi = i >> 2, a = i & 3;
    const int qj = j >> 2, c = j & 3;
    const int g = (qj - qi) & 15;
    int byteoff;
    if (g <= 8) byteoff = (g * 16 + qi) * 16 + a * 4 + c;
    else        byteoff = ((16 - g) * 16 + qj) * 16 + c * 4 + a;
    const unsigned char* p = part + (size_t)b * NSEG * (NTILE * 16) + byteoff;
    int negsum = 0;
    #pragma unroll 8
    for (int s = 0; s < NSEG; ++s)
        negsum += (int)p[s * (NTILE * 16)];
    out[idx] = (i == j) ? 0.0f
                        : fabsf((float)Sv - 2.0f * (float)negsum) * (1.0f / (float)Sv);
}

extern "C" void kernel_launch(void* const* d_in, const int* in_sizes, int n_in,
                              void* d_out, int out_size, void* d_ws, size_t ws_size,
                              hipStream_t stream) {
    const float* x = (const float*)d_in[0];            // [B, C, S] fp32
    unsigned int* u = (unsigned int*)d_ws;             // [B, C, S] u32 phase (8 MB)
    unsigned int* part = (unsigned int*)((char*)d_ws + (size_t)Bv * Cv * Sv * sizeof(unsigned int));
    float* out = (float*)d_out;                        // [B, C, C] fp32

    hipLaunchKernelGGL(hilbert_kernel, dim3(Bv * Cv / 2), dim3(256), 0, stream, x, u);
    hipLaunchKernelGGL(pli_count_kernel, dim3(Bv * NSEG), dim3(256), 0, stream, u, part);
    hipLaunchKernelGGL(finalize_kernel, dim3(Bv * Cv * Cv / 256), dim3(256), 0, stream,
                       (const unsigned char*)part, out);
}